// Round 3
// baseline (1268.037 us; speedup 1.0000x reference)
//
#include <hip/hip_runtime.h>
#include <stdint.h>

typedef unsigned short ushort_t;
typedef __attribute__((ext_vector_type(8))) short s8;    // 8 bf16 (4 VGPRs) — MFMA A/B frag
typedef __attribute__((ext_vector_type(4))) float f4;    // MFMA C/D frag / float4

#define LDK 72   // padded bf16 k-stride (144 B rows; 2-way bank alias = free on gfx950)

__device__ __forceinline__ float b2f(ushort_t u) {
    union { unsigned int i; float f; } c; c.i = ((unsigned int)u) << 16; return c.f;
}
__device__ __forceinline__ ushort_t f2b(float f) {
    union { float f; unsigned int i; } c; c.f = f;
    unsigned int b = c.i;
    b += 0x7FFFu + ((b >> 16) & 1u);   // RNE fp32 -> bf16
    return (ushort_t)(b >> 16);
}

// ---------------- node projections: Q,K,V = x @ {WQ,WK,WV} + bias (bf16 MFMA, fp32 acc) ----
__global__ __launch_bounds__(256) void node_proj_kernel(
    const float* __restrict__ x,
    const float* __restrict__ WQ, const float* __restrict__ bQ,
    const float* __restrict__ WK, const float* __restrict__ bK,
    const float* __restrict__ WV, const float* __restrict__ bV,
    ushort_t* __restrict__ Qt, ushort_t* __restrict__ Kt, ushort_t* __restrict__ Vt,
    int NN)
{
    __shared__ ushort_t sX[64 * LDK];
    __shared__ ushort_t sW[192 * LDK];   // W^T (bf16): rows = m*64 + out-col, k contiguous
    const int t = threadIdx.x;
    const int n0 = blockIdx.x * 64;

    {
        const float* Ws[3] = {WQ, WK, WV};
        int k  = t >> 3;          // 0..31
        int nc = (t & 7) * 8;     // 0..56
        for (int m = 0; m < 3; ++m) {
            #pragma unroll
            for (int rep = 0; rep < 2; ++rep) {
                int kk = k + rep * 32;
                f4 v0 = *(const f4*)(Ws[m] + kk * 64 + nc);
                f4 v1 = *(const f4*)(Ws[m] + kk * 64 + nc + 4);
                #pragma unroll
                for (int i = 0; i < 4; ++i) {
                    sW[(m * 64 + nc + i)     * LDK + kk] = f2b(v0[i]);
                    sW[(m * 64 + nc + 4 + i) * LDK + kk] = f2b(v1[i]);
                }
            }
        }
    }
    {
        int r  = t >> 2;
        int c0 = (t & 3) * 16;
        int n = n0 + r; if (n >= NN) n = NN - 1;
        const float* src = x + (size_t)n * 64 + c0;
        ushort_t tmp[16];
        #pragma unroll
        for (int q = 0; q < 4; ++q) {
            f4 v = *(const f4*)(src + q * 4);
            #pragma unroll
            for (int i = 0; i < 4; ++i) tmp[q * 4 + i] = f2b(v[i]);
        }
        *(s8*)(&sX[r * LDK + c0])     = *(s8*)(tmp);
        *(s8*)(&sX[r * LDK + c0 + 8]) = *(s8*)(tmp + 8);
    }
    __syncthreads();

    const int w = t >> 6, l = t & 63, lr = l & 15, lq = l >> 4;

    s8 a0 = *(const s8*)(&sX[(w * 16 + lr) * LDK + lq * 8]);
    s8 a1 = *(const s8*)(&sX[(w * 16 + lr) * LDK + 32 + lq * 8]);

    const float* bs[3]   = {bQ, bK, bV};
    ushort_t*    outs[3] = {Qt, Kt, Vt};

    #pragma unroll
    for (int ct = 0; ct < 12; ++ct) {
        int m  = ct >> 2;
        int cl = (ct & 3) * 16 + lr;
        s8 b0 = *(const s8*)(&sW[(ct * 16 + lr) * LDK + lq * 8]);
        s8 b1 = *(const s8*)(&sW[(ct * 16 + lr) * LDK + 32 + lq * 8]);
        float bias = bs[m][cl];
        f4 acc = {bias, bias, bias, bias};
        acc = __builtin_amdgcn_mfma_f32_16x16x32_bf16(a0, b0, acc, 0, 0, 0);
        acc = __builtin_amdgcn_mfma_f32_16x16x32_bf16(a1, b1, acc, 0, 0, 0);
        ushort_t* outp = outs[m];
        #pragma unroll
        for (int r = 0; r < 4; ++r) {          // C/D: col=lane&15, row=quad*4+r
            int n = n0 + w * 16 + lq * 4 + r;
            if (n < NN) outp[(size_t)n * 64 + cl] = f2b(acc[r]);
        }
    }
}

// ---------------- CSR build: histogram / scan / scatter ----------------
__global__ __launch_bounds__(256) void hist_kernel(
    const int* __restrict__ ei, int* __restrict__ counts, int NE)
{
    int e = blockIdx.x * blockDim.x + threadIdx.x;
    if (e < NE) atomicAdd(&counts[ei[NE + e]], 1);
}

__global__ __launch_bounds__(1024) void scan_kernel(
    const int* __restrict__ counts, int* __restrict__ offsets,
    int* __restrict__ cursor, int NN)
{
    __shared__ int sSum[1024];
    const int t = threadIdx.x;
    const int per = (NN + 1023) / 1024;
    int lo = t * per;
    int hi = lo + per; if (hi > NN) hi = NN; if (lo > NN) lo = NN;
    int s = 0;
    for (int i = lo; i < hi; ++i) s += counts[i];
    sSum[t] = s;
    __syncthreads();
    for (int d = 1; d < 1024; d <<= 1) {
        int v = (t >= d) ? sSum[t - d] : 0;
        __syncthreads();
        sSum[t] += v;
        __syncthreads();
    }
    int run = (t == 0) ? 0 : sSum[t - 1];
    for (int i = lo; i < hi; ++i) {
        offsets[i] = run;
        cursor[i]  = run;
        run += counts[i];
    }
    if (t == 1023) offsets[NN] = run;   // run == grand total for the last thread
}

__global__ __launch_bounds__(256) void scatter_kernel(
    const int* __restrict__ ei, int* __restrict__ cursor,
    int* __restrict__ perm, int NE)
{
    int e = blockIdx.x * blockDim.x + threadIdx.x;
    if (e < NE) {
        int pos = atomicAdd(&cursor[ei[NE + e]], 1);
        perm[pos] = e;
    }
}

// ---------------- edge scores: E-proj (MFMA fused) + exp(clip(KQE/sqrt(d))) ----------------
__global__ __launch_bounds__(256) void edge_score_kernel(
    const float* __restrict__ edge_attr,
    const int* __restrict__ edge_index,
    const float* __restrict__ WE, const float* __restrict__ bE,
    const ushort_t* __restrict__ Qt, const ushort_t* __restrict__ Kt,
    float* __restrict__ score,
    int NE)
{
    __shared__ ushort_t sW[64 * LDK];
    __shared__ ushort_t sA[64 * LDK];
    __shared__ float    sE[64 * 65];   // fp32 E tile, +1 pad

    const int t  = threadIdx.x;
    const int e0 = blockIdx.x * 64;

    // stage WE^T (fp32 -> bf16)
    {
        int k  = t >> 3;
        int nc = (t & 7) * 8;
        #pragma unroll
        for (int rep = 0; rep < 2; ++rep) {
            int kk = k + rep * 32;
            f4 v0 = *(const f4*)(WE + kk * 64 + nc);
            f4 v1 = *(const f4*)(WE + kk * 64 + nc + 4);
            #pragma unroll
            for (int i = 0; i < 4; ++i) {
                sW[(nc + i)     * LDK + kk] = f2b(v0[i]);
                sW[(nc + 4 + i) * LDK + kk] = f2b(v1[i]);
            }
        }
    }
    // stage edge_attr tile (fp32 -> bf16)
    {
        int r  = t >> 2;
        int c0 = (t & 3) * 16;
        long e = e0 + r; if (e >= NE) e = NE - 1;
        const float* src = edge_attr + e * 64 + c0;
        ushort_t tmp[16];
        #pragma unroll
        for (int q = 0; q < 4; ++q) {
            f4 v = *(const f4*)(src + q * 4);
            #pragma unroll
            for (int i = 0; i < 4; ++i) tmp[q * 4 + i] = f2b(v[i]);
        }
        *(s8*)(&sA[r * LDK + c0])     = *(s8*)(tmp);
        *(s8*)(&sA[r * LDK + c0 + 8]) = *(s8*)(tmp + 8);
    }
    __syncthreads();

    const int w = t >> 6, l = t & 63, lr = l & 15, lq = l >> 4;

    s8 a0 = *(const s8*)(&sA[(w * 16 + lr) * LDK + lq * 8]);
    s8 a1 = *(const s8*)(&sA[(w * 16 + lr) * LDK + 32 + lq * 8]);

    #pragma unroll
    for (int ct = 0; ct < 4; ++ct) {
        s8 b0 = *(const s8*)(&sW[(ct * 16 + lr) * LDK + lq * 8]);
        s8 b1 = *(const s8*)(&sW[(ct * 16 + lr) * LDK + 32 + lq * 8]);
        float bias = bE[ct * 16 + lr];
        f4 acc = {bias, bias, bias, bias};
        acc = __builtin_amdgcn_mfma_f32_16x16x32_bf16(a0, b0, acc, 0, 0, 0);
        acc = __builtin_amdgcn_mfma_f32_16x16x32_bf16(a1, b1, acc, 0, 0, 0);
        #pragma unroll
        for (int r = 0; r < 4; ++r)
            sE[(w * 16 + lq * 4 + r) * 65 + ct * 16 + lr] = acc[r];   // E stays fp32
    }
    __syncthreads();

    const float inv_sqrt_d = 0.25f;   // 1/sqrt(16)
    const int j = l, h = l >> 4;

    #pragma unroll 4
    for (int i = 0; i < 16; ++i) {
        int el = w * 16 + i;
        int e  = e0 + el;
        if (e < NE) {
            int src = edge_index[e];
            int dst = edge_index[NE + e];
            float p = b2f(Kt[(size_t)src * 64 + j]) * b2f(Qt[(size_t)dst * 64 + j]) * sE[el * 65 + j];
            // per-head (16-lane) reduce — xor masks stay inside the head group
            p += __shfl_xor(p, 1);
            p += __shfl_xor(p, 2);
            p += __shfl_xor(p, 4);
            p += __shfl_xor(p, 8);
            float s = p * inv_sqrt_d;
            s = fminf(fmaxf(s, -5.f), 5.f);
            float sc = __expf(s);
            if ((j & 15) == 0) score[(size_t)e * 4 + h] = sc;   // 4 lanes -> 16B contiguous
        }
    }
}

// ---------------- aggregate: wave per dst node, fused finalize ----------------
__global__ __launch_bounds__(256) void aggregate_kernel(
    const int* __restrict__ perm, const int* __restrict__ offsets,
    const int* __restrict__ ei, const float* __restrict__ score,
    const ushort_t* __restrict__ Vt, float* __restrict__ out, int NN)
{
    int n = blockIdx.x * 4 + (threadIdx.x >> 6);
    if (n >= NN) return;
    const int l = threadIdx.x & 63;
    const int h = l >> 4;
    int k0 = offsets[n], k1 = offsets[n + 1];
    float acc = 0.f, z = 0.f;
    int k = k0;
    // 2-wide to overlap the perm -> (src,score) -> V dependency chains
    for (; k + 2 <= k1; k += 2) {
        int eA = perm[k], eB = perm[k + 1];
        int sA = ei[eA],  sB = ei[eB];
        float cA = score[(size_t)eA * 4 + h];
        float cB = score[(size_t)eB * 4 + h];
        float vA = b2f(Vt[(size_t)sA * 64 + l]);
        float vB = b2f(Vt[(size_t)sB * 64 + l]);
        acc = fmaf(vA, cA, acc);
        acc = fmaf(vB, cB, acc);
        z += cA + cB;
    }
    if (k < k1) {
        int eA = perm[k];
        int sA = ei[eA];
        float cA = score[(size_t)eA * 4 + h];
        float vA = b2f(Vt[(size_t)sA * 64 + l]);
        acc = fmaf(vA, cA, acc);
        z += cA;
    }
    out[(size_t)n * 64 + l] = acc / (z + 1e-6f);
}

extern "C" void kernel_launch(void* const* d_in, const int* in_sizes, int n_in,
                              void* d_out, int out_size, void* d_ws, size_t ws_size,
                              hipStream_t stream)
{
    const float* x  = (const float*)d_in[0];
    const float* ea = (const float*)d_in[1];
    const int*   ei = (const int*)d_in[2];
    const float* WQ = (const float*)d_in[3];
    const float* bQ = (const float*)d_in[4];
    const float* WK = (const float*)d_in[5];
    const float* bK = (const float*)d_in[6];
    const float* WE = (const float*)d_in[7];
    const float* bE = (const float*)d_in[8];
    const float* WV = (const float*)d_in[9];
    const float* bV = (const float*)d_in[10];

    const int NN = in_sizes[0] / 64;
    const int NE = in_sizes[1] / 64;

    char* ws = (char*)d_ws;
    size_t off = 0;
    auto alloc = [&](size_t bytes) {
        void* p = ws + off;
        off = (off + bytes + 255) & ~(size_t)255;
        return p;
    };
    ushort_t* Qt      = (ushort_t*)alloc((size_t)NN * 64 * 2);
    ushort_t* Kt      = (ushort_t*)alloc((size_t)NN * 64 * 2);
    ushort_t* Vt      = (ushort_t*)alloc((size_t)NN * 64 * 2);
    float*    score   = (float*)   alloc((size_t)NE * 4 * 4);
    int*      counts  = (int*)     alloc((size_t)NN * 4);
    int*      offsets = (int*)     alloc(((size_t)NN + 1) * 4);
    int*      cursor  = (int*)     alloc((size_t)NN * 4);
    int*      perm    = (int*)     alloc((size_t)NE * 4);

    hipMemsetAsync(counts, 0, (size_t)NN * 4, stream);

    node_proj_kernel<<<(NN + 63) / 64, 256, 0, stream>>>(
        x, WQ, bQ, WK, bK, WV, bV, Qt, Kt, Vt, NN);

    hist_kernel<<<(NE + 255) / 256, 256, 0, stream>>>(ei, counts, NE);
    scan_kernel<<<1, 1024, 0, stream>>>(counts, offsets, cursor, NN);
    scatter_kernel<<<(NE + 255) / 256, 256, 0, stream>>>(ei, cursor, perm, NE);

    edge_score_kernel<<<(NE + 63) / 64, 256, 0, stream>>>(
        ea, ei, WE, bE, Qt, Kt, score, NE);

    aggregate_kernel<<<(NN + 3) / 4, 256, 0, stream>>>(
        perm, offsets, ei, score, Vt, (float*)d_out, NN);
}

// Round 4
// 990.331 us; speedup vs baseline: 1.2804x; 1.2804x over previous
//
#include <hip/hip_runtime.h>
#include <stdint.h>

typedef unsigned short ushort_t;
typedef __attribute__((ext_vector_type(8))) short s8;    // 8 bf16 (4 VGPRs) — MFMA A/B frag
typedef __attribute__((ext_vector_type(4))) float f4;    // MFMA C/D frag / float4

#define LDK 72   // padded bf16 k-stride (144 B rows)
#define LDE 68   // fp32 E-tile stride (16B-aligned rows, bank stride 4)

__device__ __forceinline__ float b2f(ushort_t u) {
    union { unsigned int i; float f; } c; c.i = ((unsigned int)u) << 16; return c.f;
}
__device__ __forceinline__ ushort_t f2b(float f) {
    union { float f; unsigned int i; } c; c.f = f;
    unsigned int b = c.i;
    b += 0x7FFFu + ((b >> 16) & 1u);   // RNE fp32 -> bf16
    return (ushort_t)(b >> 16);
}

// ---------------- node projections: Q,K,V = x @ {WQ,WK,WV} + bias (bf16 MFMA, fp32 acc) ----
__global__ __launch_bounds__(256) void node_proj_kernel(
    const float* __restrict__ x,
    const float* __restrict__ WQ, const float* __restrict__ bQ,
    const float* __restrict__ WK, const float* __restrict__ bK,
    const float* __restrict__ WV, const float* __restrict__ bV,
    ushort_t* __restrict__ Qt, ushort_t* __restrict__ Kt, ushort_t* __restrict__ Vt,
    int NN)
{
    __shared__ ushort_t sX[64 * LDK];
    __shared__ ushort_t sW[192 * LDK];   // W^T (bf16): rows = m*64 + out-col, k contiguous
    const int t = threadIdx.x;
    const int n0 = blockIdx.x * 64;

    {
        const float* Ws[3] = {WQ, WK, WV};
        int k  = t >> 3;          // 0..31
        int nc = (t & 7) * 8;     // 0..56
        for (int m = 0; m < 3; ++m) {
            #pragma unroll
            for (int rep = 0; rep < 2; ++rep) {
                int kk = k + rep * 32;
                f4 v0 = *(const f4*)(Ws[m] + kk * 64 + nc);
                f4 v1 = *(const f4*)(Ws[m] + kk * 64 + nc + 4);
                #pragma unroll
                for (int i = 0; i < 4; ++i) {
                    sW[(m * 64 + nc + i)     * LDK + kk] = f2b(v0[i]);
                    sW[(m * 64 + nc + 4 + i) * LDK + kk] = f2b(v1[i]);
                }
            }
        }
    }
    {
        int r  = t >> 2;
        int c0 = (t & 3) * 16;
        int n = n0 + r; if (n >= NN) n = NN - 1;
        const float* src = x + (size_t)n * 64 + c0;
        ushort_t tmp[16];
        #pragma unroll
        for (int q = 0; q < 4; ++q) {
            f4 v = *(const f4*)(src + q * 4);
            #pragma unroll
            for (int i = 0; i < 4; ++i) tmp[q * 4 + i] = f2b(v[i]);
        }
        *(s8*)(&sX[r * LDK + c0])     = *(s8*)(tmp);
        *(s8*)(&sX[r * LDK + c0 + 8]) = *(s8*)(tmp + 8);
    }
    __syncthreads();

    const int w = t >> 6, l = t & 63, lr = l & 15, lq = l >> 4;

    s8 a0 = *(const s8*)(&sX[(w * 16 + lr) * LDK + lq * 8]);
    s8 a1 = *(const s8*)(&sX[(w * 16 + lr) * LDK + 32 + lq * 8]);

    const float* bs[3]   = {bQ, bK, bV};
    ushort_t*    outs[3] = {Qt, Kt, Vt};

    #pragma unroll
    for (int ct = 0; ct < 12; ++ct) {
        int m  = ct >> 2;
        int cl = (ct & 3) * 16 + lr;
        s8 b0 = *(const s8*)(&sW[(ct * 16 + lr) * LDK + lq * 8]);
        s8 b1 = *(const s8*)(&sW[(ct * 16 + lr) * LDK + 32 + lq * 8]);
        float bias = bs[m][cl];
        f4 acc = {bias, bias, bias, bias};
        acc = __builtin_amdgcn_mfma_f32_16x16x32_bf16(a0, b0, acc, 0, 0, 0);
        acc = __builtin_amdgcn_mfma_f32_16x16x32_bf16(a1, b1, acc, 0, 0, 0);
        ushort_t* outp = outs[m];
        #pragma unroll
        for (int r = 0; r < 4; ++r) {          // C/D: col=lane&15, row=quad*4+r
            int n = n0 + w * 16 + lq * 4 + r;
            if (n < NN) outp[(size_t)n * 64 + cl] = f2b(acc[r]);
        }
    }
}

// ---------------- CSR build: histogram / scan / scatter ----------------
__global__ __launch_bounds__(256) void hist_kernel(
    const int* __restrict__ ei, int* __restrict__ counts, int NE)
{
    int e = blockIdx.x * blockDim.x + threadIdx.x;
    if (e < NE) atomicAdd(&counts[ei[NE + e]], 1);
}

__global__ __launch_bounds__(1024) void scan_kernel(
    const int* __restrict__ counts, int* __restrict__ offsets,
    int* __restrict__ cursor, int NN)
{
    __shared__ int sSum[1024];
    const int t = threadIdx.x;
    const int per = (NN + 1023) / 1024;
    int lo = t * per;
    int hi = lo + per; if (hi > NN) hi = NN; if (lo > NN) lo = NN;
    int s = 0;
    for (int i = lo; i < hi; ++i) s += counts[i];
    sSum[t] = s;
    __syncthreads();
    for (int d = 1; d < 1024; d <<= 1) {
        int v = (t >= d) ? sSum[t - d] : 0;
        __syncthreads();
        sSum[t] += v;
        __syncthreads();
    }
    int run = (t == 0) ? 0 : sSum[t - 1];
    for (int i = lo; i < hi; ++i) {
        offsets[i] = run;
        cursor[i]  = run;
        run += counts[i];
    }
    if (t == 1023) offsets[NN] = run;
}

__global__ __launch_bounds__(256) void scatter_kernel(
    const int* __restrict__ ei, int* __restrict__ cursor,
    int* __restrict__ perm, int NE)
{
    int e = blockIdx.x * blockDim.x + threadIdx.x;
    if (e < NE) {
        int pos = atomicAdd(&cursor[ei[NE + e]], 1);
        perm[pos] = e;
    }
}

// ---------------- edge scores: E-proj (MFMA) + exp(clip(KQE/sqrt(d))) ----------------
// Scatter phase lane mapping: lane l -> edge (l>>2), head (l&3). Straight-line,
// 4 independent s8 gathers fetch 16 K-rows + 16 Q-rows at once; no shuffles.
__global__ __launch_bounds__(256) void edge_score_kernel(
    const float* __restrict__ edge_attr,
    const int* __restrict__ edge_index,
    const float* __restrict__ WE, const float* __restrict__ bE,
    const ushort_t* __restrict__ Qt, const ushort_t* __restrict__ Kt,
    float* __restrict__ score,
    int NE)
{
    __shared__ ushort_t sW[64 * LDK];
    __shared__ ushort_t sA[64 * LDK];
    __shared__ float    sE[64 * LDE];   // fp32 E tile

    const int t  = threadIdx.x;
    const int e0 = blockIdx.x * 64;

    // stage WE^T (fp32 -> bf16)
    {
        int k  = t >> 3;
        int nc = (t & 7) * 8;
        #pragma unroll
        for (int rep = 0; rep < 2; ++rep) {
            int kk = k + rep * 32;
            f4 v0 = *(const f4*)(WE + kk * 64 + nc);
            f4 v1 = *(const f4*)(WE + kk * 64 + nc + 4);
            #pragma unroll
            for (int i = 0; i < 4; ++i) {
                sW[(nc + i)     * LDK + kk] = f2b(v0[i]);
                sW[(nc + 4 + i) * LDK + kk] = f2b(v1[i]);
            }
        }
    }
    // stage edge_attr tile (fp32 -> bf16)
    {
        int r  = t >> 2;
        int c0 = (t & 3) * 16;
        long e = e0 + r; if (e >= NE) e = NE - 1;
        const float* src = edge_attr + e * 64 + c0;
        ushort_t tmp[16];
        #pragma unroll
        for (int q = 0; q < 4; ++q) {
            f4 v = *(const f4*)(src + q * 4);
            #pragma unroll
            for (int i = 0; i < 4; ++i) tmp[q * 4 + i] = f2b(v[i]);
        }
        *(s8*)(&sA[r * LDK + c0])     = *(s8*)(tmp);
        *(s8*)(&sA[r * LDK + c0 + 8]) = *(s8*)(tmp + 8);
    }
    __syncthreads();

    const int w = t >> 6, l = t & 63, lr = l & 15, lq = l >> 4;

    s8 a0 = *(const s8*)(&sA[(w * 16 + lr) * LDK + lq * 8]);
    s8 a1 = *(const s8*)(&sA[(w * 16 + lr) * LDK + 32 + lq * 8]);

    #pragma unroll
    for (int ct = 0; ct < 4; ++ct) {
        s8 b0 = *(const s8*)(&sW[(ct * 16 + lr) * LDK + lq * 8]);
        s8 b1 = *(const s8*)(&sW[(ct * 16 + lr) * LDK + 32 + lq * 8]);
        float bias = bE[ct * 16 + lr];
        f4 acc = {bias, bias, bias, bias};
        acc = __builtin_amdgcn_mfma_f32_16x16x32_bf16(a0, b0, acc, 0, 0, 0);
        acc = __builtin_amdgcn_mfma_f32_16x16x32_bf16(a1, b1, acc, 0, 0, 0);
        #pragma unroll
        for (int r = 0; r < 4; ++r)
            sE[(w * 16 + lq * 4 + r) * LDE + ct * 16 + lr] = acc[r];   // fp32, 2-way bank alias = free
    }
    __syncthreads();

    // ---- score phase: lane = (edge, head) ----
    const int i  = l >> 2;          // edge within wave's 16
    const int h  = l & 3;           // head
    const int el = w * 16 + i;
    const int e  = e0 + el;

    float sc = 0.f;
    if (e < NE) {
        int src = edge_index[e];
        int dst = edge_index[NE + e];
        const ushort_t* kp = Kt + (size_t)src * 64 + h * 16;
        const ushort_t* qp = Qt + (size_t)dst * 64 + h * 16;
        // 4 independent 16B gathers (16 rows per instruction across the wave)
        s8 k0 = *(const s8*)(kp);
        s8 k1 = *(const s8*)(kp + 8);
        s8 q0 = *(const s8*)(qp);
        s8 q1 = *(const s8*)(qp + 8);
        const float* ep = &sE[el * LDE + h * 16];
        f4 E0 = *(const f4*)(ep);
        f4 E1 = *(const f4*)(ep + 4);
        f4 E2 = *(const f4*)(ep + 8);
        f4 E3 = *(const f4*)(ep + 12);

        float p = 0.f;
        #pragma unroll
        for (int d = 0; d < 4; ++d) p = fmaf(b2f(((ushort_t*)&k0)[d])     * b2f(((ushort_t*)&q0)[d]),     E0[d], p);
        #pragma unroll
        for (int d = 0; d < 4; ++d) p = fmaf(b2f(((ushort_t*)&k0)[d + 4]) * b2f(((ushort_t*)&q0)[d + 4]), E1[d], p);
        #pragma unroll
        for (int d = 0; d < 4; ++d) p = fmaf(b2f(((ushort_t*)&k1)[d])     * b2f(((ushort_t*)&q1)[d]),     E2[d], p);
        #pragma unroll
        for (int d = 0; d < 4; ++d) p = fmaf(b2f(((ushort_t*)&k1)[d + 4]) * b2f(((ushort_t*)&q1)[d + 4]), E3[d], p);

        float s = p * 0.25f;                    // 1/sqrt(16)
        s = fminf(fmaxf(s, -5.f), 5.f);
        sc = __expf(s);
        score[(size_t)e * 4 + h] = sc;          // 64 lanes -> 256B coalesced
    }
}

// ---------------- aggregate: wave per dst node, 8-wide batched, fused finalize ----------------
__global__ __launch_bounds__(256) void aggregate_kernel(
    const int* __restrict__ perm, const int* __restrict__ offsets,
    const int* __restrict__ ei, const float* __restrict__ score,
    const ushort_t* __restrict__ Vt, float* __restrict__ out, int NN)
{
    int n = blockIdx.x * 4 + (threadIdx.x >> 6);
    if (n >= NN) return;
    const int l = threadIdx.x & 63;
    const int h = l >> 4;
    int k0 = offsets[n], k1 = offsets[n + 1];
    float acc = 0.f, z = 0.f;
    int k = k0;
    // 8-wide: 3 rounds of independent loads per 8 edges (perm -> ei/score -> Vt)
    for (; k + 8 <= k1; k += 8) {
        int e[8], s[8];
        float c[8], v[8];
        #pragma unroll
        for (int j = 0; j < 8; ++j) e[j] = perm[k + j];
        #pragma unroll
        for (int j = 0; j < 8; ++j) { s[j] = ei[e[j]]; c[j] = score[(size_t)e[j] * 4 + h]; }
        #pragma unroll
        for (int j = 0; j < 8; ++j) v[j] = b2f(Vt[(size_t)s[j] * 64 + l]);
        #pragma unroll
        for (int j = 0; j < 8; ++j) { acc = fmaf(v[j], c[j], acc); z += c[j]; }
    }
    for (; k < k1; ++k) {
        int eA = perm[k];
        int sA = ei[eA];
        float cA = score[(size_t)eA * 4 + h];
        float vA = b2f(Vt[(size_t)sA * 64 + l]);
        acc = fmaf(vA, cA, acc);
        z += cA;
    }
    out[(size_t)n * 64 + l] = acc / (z + 1e-6f);
}

extern "C" void kernel_launch(void* const* d_in, const int* in_sizes, int n_in,
                              void* d_out, int out_size, void* d_ws, size_t ws_size,
                              hipStream_t stream)
{
    const float* x  = (const float*)d_in[0];
    const float* ea = (const float*)d_in[1];
    const int*   ei = (const int*)d_in[2];
    const float* WQ = (const float*)d_in[3];
    const float* bQ = (const float*)d_in[4];
    const float* WK = (const float*)d_in[5];
    const float* bK = (const float*)d_in[6];
    const float* WE = (const float*)d_in[7];
    const float* bE = (const float*)d_in[8];
    const float* WV = (const float*)d_in[9];
    const float* bV = (const float*)d_in[10];

    const int NN = in_sizes[0] / 64;
    const int NE = in_sizes[1] / 64;

    char* ws = (char*)d_ws;
    size_t off = 0;
    auto alloc = [&](size_t bytes) {
        void* p = ws + off;
        off = (off + bytes + 255) & ~(size_t)255;
        return p;
    };
    ushort_t* Qt      = (ushort_t*)alloc((size_t)NN * 64 * 2);
    ushort_t* Kt      = (ushort_t*)alloc((size_t)NN * 64 * 2);
    ushort_t* Vt      = (ushort_t*)alloc((size_t)NN * 64 * 2);
    float*    score   = (float*)   alloc((size_t)NE * 4 * 4);
    int*      counts  = (int*)     alloc((size_t)NN * 4);
    int*      offsets = (int*)     alloc(((size_t)NN + 1) * 4);
    int*      cursor  = (int*)     alloc((size_t)NN * 4);
    int*      perm    = (int*)     alloc((size_t)NE * 4);

    hipMemsetAsync(counts, 0, (size_t)NN * 4, stream);

    node_proj_kernel<<<(NN + 63) / 64, 256, 0, stream>>>(
        x, WQ, bQ, WK, bK, WV, bV, Qt, Kt, Vt, NN);

    hist_kernel<<<(NE + 255) / 256, 256, 0, stream>>>(ei, counts, NE);
    scan_kernel<<<1, 1024, 0, stream>>>(counts, offsets, cursor, NN);
    scatter_kernel<<<(NE + 255) / 256, 256, 0, stream>>>(ei, cursor, perm, NE);

    edge_score_kernel<<<(NE + 63) / 64, 256, 0, stream>>>(
        ea, ei, WE, bE, Qt, Kt, score, NE);

    aggregate_kernel<<<(NN + 3) / 4, 256, 0, stream>>>(
        perm, offsets, ei, score, Vt, (float*)d_out, NN);
}